// Round 7
// baseline (1118.504 us; speedup 1.0000x reference)
//
#include <hip/hip_runtime.h>
#include <cstdint>

// LSTM: B=1024, T=336, I=64, H=256, gates 4H=1024, K = I+H = 320.
// R7: 128 batch-groups (8 batch each) x 2 member-WGs = 256 WGs (1/CU).
// Each member owns 128 h-cols (512 gate rows) in VGPR A-fragments.
// Fan-in 1: each WG polls exactly ONE partner; each thread polls ONE 8B
// tagged pair (IF-scope sc0 sc1 -- the R3/R5-proven protocol). Register
// cell (r16 = 4*col+gate remap), bias as acc-init, one barrier/step,
// own-slice via LDS, x prefetched one step ahead.

#define GROUPS  128
#define BATCH_G 8
#define T_STEPS 336
#define I_DIM   64
#define H_DIM   256
#define VSTRIDE 336      // ushorts per staged batch row (K=320 + pad)
#define NROWS   16       // staged rows (8 valid batch + 8 dummy for MFMA N=16)
#define PAIRS_M 64       // h col-pairs per member slice (128 cols / 2)
#define OUT_HALF 262144  // 1024*256
// uint2 slots per buffer: 128 groups * 2 members * 64 pairs * 8 batch
#define BUF_STRIDE (GROUPS * 2 * PAIRS_M * BATCH_G)
#define HBUF_BYTES (2u * BUF_STRIDE * 8u)   // 2 MB

typedef __attribute__((ext_vector_type(8))) __bf16 bf16x8;
typedef __attribute__((ext_vector_type(8))) unsigned short ushort8_t;
typedef __attribute__((ext_vector_type(4))) float f32x4;
typedef __attribute__((ext_vector_type(4))) unsigned uint32x4;
typedef __attribute__((ext_vector_type(2))) unsigned uint32x2;

__device__ inline unsigned short f2bf(float f) {
  unsigned u = __builtin_bit_cast(unsigned, f);
  return (unsigned short)((u + 0x7fffu + ((u >> 16) & 1u)) >> 16);
}
__device__ inline float sigf(float x) { return 1.f / (1.f + __expf(-x)); }
__device__ inline float tanhfast(float x) { return 1.f - 2.f / (1.f + __expf(2.f * x)); }

// ---- IF-scope (cross-XCD) tagged-pair ops: sc0 sc1 (proven R3/R5) ----
__device__ inline uint32x2 ld_pair_if(const uint32x2* p) {
  uint32x2 v;
  asm volatile("global_load_dwordx2 %0, %1, off sc0 sc1\n\t"
               "s_waitcnt vmcnt(0)"
               : "=v"(v) : "v"(p) : "memory");
  return v;
}
__device__ inline void st_pair_if(uint32x2* p, uint32x2 v) {
  asm volatile("global_store_dwordx2 %0, %1, off sc0 sc1" :: "v"(p), "v"(v) : "memory");
}

__global__ __launch_bounds__(512, 2) void lstm_persistent(
    const float* __restrict__ x, const float* __restrict__ W_ih,
    const float* __restrict__ W_hh, const float* __restrict__ b_ih,
    const float* __restrict__ b_hh, float* __restrict__ out,
    uint32x2* __restrict__ hbuf)
{
  __shared__ __align__(16) unsigned short v_lds[2][NROWS * VSTRIDE];

  const int tid  = threadIdx.x;
  const int gid  = blockIdx.x >> 1;   // batch group 0..127 (batches [8*gid, +8))
  const int mid  = blockIdx.x & 1;    // member: owns h cols [mid*128, +128)
  const int wv   = tid >> 6;          // wave 0..7: cols [mid*128 + wv*16, +16)
  const int l    = tid & 63;
  const int l15  = l & 15, quad = l >> 4;

  // ---- zero both LDS staging buffers (h_0 = 0; dummy rows defined) ----
  for (int i = tid; i < 2 * NROWS * VSTRIDE / 2; i += 512)
    ((unsigned*)v_lds)[i] = 0u;

  // ---- A-fragments: 4 row-tiles per wave, local row r16 = 4*col_off + gate ----
  // tile rt covers global cols mid*128 + wv*16 + rt*4 + (0..3).
  bf16x8 afrag[4][10];
#pragma unroll
  for (int rt = 0; rt < 4; ++rt) {
    int grow = (l15 & 3) * H_DIM + mid * 128 + wv * 16 + rt * 4 + (l15 >> 2);
    const float* wih_row = W_ih + (long)grow * I_DIM;
    const float* whh_row = W_hh + (long)grow * H_DIM;
#pragma unroll
    for (int kt = 0; kt < 10; ++kt) {
      int kbase = kt * 32 + quad * 8;
      ushort8_t a;
#pragma unroll
      for (int e = 0; e < 8; ++e) {
        int k = kbase + e;
        float v = (k < I_DIM) ? wih_row[k] : whh_row[k - I_DIM];
        a[e] = f2bf(v);
      }
      afrag[rt][kt] = __builtin_bit_cast(bf16x8, a);
    }
  }

  // ---- bias as acc-init: lane's cell (tile rt) = (col_off = quad, batch = l15) ----
  f32x4 bias[4];
#pragma unroll
  for (int rt = 0; rt < 4; ++rt) {
#pragma unroll
    for (int g = 0; g < 4; ++g) {
      int grow = g * H_DIM + mid * 128 + wv * 16 + rt * 4 + quad;
      bias[rt][g] = b_ih[grow] + b_hh[grow];
    }
  }

  float c_reg[4] = {0.f, 0.f, 0.f, 0.f};
  float h_keep[4];

  // ---- x staging: 128 threads, 1 float4 each (8 rows x 16 thr) ----
  const int xb_row = tid >> 4;           // 0..7 (valid for tid<128)
  const int x_i4   = (tid & 15) * 4;
  const long xrow_base = ((long)(gid * BATCH_G + xb_row)) * T_STEPS * I_DIM;

  // ---- producer store: slot ((gid*2+mid)*64 + pp)*8 + batch ----
  //      pp = wv*8 + rt*2 + (quad>>1); lanes l15(=batch)<8 contiguous 64B.
  uint32x2* st_base = hbuf + (((long)gid * 2 + mid) * PAIRS_M + wv * 8 + (quad >> 1)) * BATCH_G + l15;

  // ---- consumer poll: ONE 8B pair per thread, from partner slice ----
  const int p_pp = tid >> 3;             // 0..63
  const int p_b  = tid & 7;
  const uint32x2* poll_p = hbuf + (((long)gid * 2 + (mid ^ 1)) * PAIRS_M + p_pp) * BATCH_G + p_b;

  float4 xv;
  if (tid < 128) xv = *(const float4*)(x + xrow_base);   // prefetch t=1

  __syncthreads();   // LDS zeros visible

  for (int t = 1; t <= T_STEPS; ++t) {
    unsigned short* vbuf = v_lds[t & 1];

    // ---- stage prefetched x_t (fp32 -> bf16) ----
    if (tid < 128) {
      ushort4 xb;
      xb.x = f2bf(xv.x); xb.y = f2bf(xv.y); xb.z = f2bf(xv.z); xb.w = f2bf(xv.w);
      *(ushort4*)&vbuf[xb_row * VSTRIDE + x_i4] = xb;
    }

    // ---- stage partner h_{t-1}: poll the tagged pair directly ----
    if (t > 1) {
      const unsigned tag = (unsigned)(t - 1);
      const uint32x2* src = poll_p + ((t - 1) & 1) * BUF_STRIDE;
      uint32x2 v;
      int it = 0;
      for (;;) {
        v = ld_pair_if(src);
        if (v[0] == tag) break;
        if (++it > (1 << 14)) break;   // safety valve vs. hang
      }
      *(unsigned*)&vbuf[p_b * VSTRIDE + I_DIM + (mid ^ 1) * 128 + 2 * p_pp] = v[1];
    }
    __syncthreads();   // the ONLY barrier per step (v_lds double-buffered)

    // ---- prefetch x_{t+1} (in flight during MFMA + cell) ----
    if (t < T_STEPS && tid < 128)
      xv = *(const float4*)(x + xrow_base + (long)t * I_DIM + x_i4);

    // ---- MFMA: 4 row-tiles x 10 k-tiles, B shared across tiles ----
    f32x4 acc0 = bias[0], acc1 = bias[1], acc2 = bias[2], acc3 = bias[3];
    const unsigned short* vb = vbuf + (unsigned)l15 * VSTRIDE + quad * 8;
#pragma unroll
    for (int kt = 0; kt < 10; ++kt) {
      bf16x8 bv = __builtin_bit_cast(bf16x8, *(const uint32x4*)(vb + kt * 32));
      acc0 = __builtin_amdgcn_mfma_f32_16x16x32_bf16(afrag[0][kt], bv, acc0, 0, 0, 0);
      acc1 = __builtin_amdgcn_mfma_f32_16x16x32_bf16(afrag[1][kt], bv, acc1, 0, 0, 0);
      acc2 = __builtin_amdgcn_mfma_f32_16x16x32_bf16(afrag[2][kt], bv, acc2, 0, 0, 0);
      acc3 = __builtin_amdgcn_mfma_f32_16x16x32_bf16(afrag[3][kt], bv, acc3, 0, 0, 0);
    }

    // ---- cell in registers; own-slice to next LDS buffer; tagged pair to partner ----
    unsigned short* next_own = v_lds[(t + 1) & 1] + l15 * VSTRIDE + I_DIM + mid * 128 + wv * 16;
    const bool valid = (l15 < BATCH_G);
#pragma unroll
    for (int rt = 0; rt < 4; ++rt) {
      const f32x4 acc = (rt == 0) ? acc0 : (rt == 1) ? acc1 : (rt == 2) ? acc2 : acc3;
      float c = sigf(acc[1]) * c_reg[rt] + sigf(acc[0]) * tanhfast(acc[2]);
      float h = sigf(acc[3]) * tanhfast(c);
      c_reg[rt] = c; h_keep[rt] = h;
      unsigned short hb16 = f2bf(h);
      if (valid) next_own[rt * 4 + quad] = hb16;                 // LDS shortcut (own WG)
      unsigned hb = (unsigned)hb16;
      unsigned partner = (unsigned)__shfl_xor((int)hb, 16, 64);  // quad^1: col^1, same batch
      if (valid && !(quad & 1)) {
        uint32x2 pv;
        pv[0] = (unsigned)t;                 // tag
        pv[1] = hb | (partner << 16);        // (col, col+1)
        st_pair_if(st_base + rt * 2 * BATCH_G + (t & 1) * BUF_STRIDE, pv);  // fire-and-forget
      }
    }
  }

  // ---- outputs: h_T then c_T, fp32 (pre-bf16-rounding values) ----
  if (l15 < BATCH_G) {
#pragma unroll
    for (int rt = 0; rt < 4; ++rt) {
      int gcol = mid * 128 + wv * 16 + rt * 4 + quad;
      long o = (long)(gid * BATCH_G + l15) * H_DIM + gcol;
      out[o]            = h_keep[rt];
      out[OUT_HALF + o] = c_reg[rt];
    }
  }
}

extern "C" void kernel_launch(void* const* d_in, const int* in_sizes, int n_in,
                              void* d_out, int out_size, void* d_ws, size_t ws_size,
                              hipStream_t stream) {
  const float* x    = (const float*)d_in[0];
  const float* W_ih = (const float*)d_in[1];
  const float* W_hh = (const float*)d_in[2];
  const float* b_ih = (const float*)d_in[3];
  const float* b_hh = (const float*)d_in[4];
  float* out = (float*)d_out;

  uint32x2* hbuf = (uint32x2*)d_ws;   // 2 MB exchange (tag,data pairs)

  // Clear tags so no stale value can match t in [1,336].
  hipMemsetAsync(d_ws, 0, HBUF_BYTES, stream);
  lstm_persistent<<<dim3(256), dim3(512), 0, stream>>>(x, W_ih, W_hh, b_ih, b_hh, out, hbuf);
}